// Round 14
// baseline (152.008 us; speedup 1.0000x reference)
//
#include <hip/hip_runtime.h>

#define NPTS 16384
#define PW 16
#define NCH 5
#define NU (1.0f / 100.0f)

typedef _Float16 f16;
typedef __attribute__((ext_vector_type(4))) _Float16 f16x4;
typedef __attribute__((ext_vector_type(8))) _Float16 f16x8;
typedef __attribute__((ext_vector_type(4))) float f32x4;

// granule swizzle within a 64-granule (16B each) tile: bijective, same on
// write and read; spreads writes/reads over all bank groups.
__device__ __forceinline__ int swz(int g) { return g ^ ((g >> 3) & 7); }

// ---- prep: W1..W5 (256x256) and W6 (256x3 zero-padded to 16 cols) -> MFMA
// fragment order, single f16 plane. Fragment (16x16x32): lane l holds
// M[k = kc*32 + 8*(l>>4) + j][col = nf*16 + (l&15)], j=0..7. Serves as the
// A-operand (A[m=col][k] = W^T) in the transposed GEMM.
__global__ __launch_bounds__(256) void prep_kernel(
    const float* __restrict__ W1, const float* __restrict__ W2,
    const float* __restrict__ W3, const float* __restrict__ W4,
    const float* __restrict__ W5, const float* __restrict__ W6,
    f16* __restrict__ bh, f16* __restrict__ b6h)
{
    int idx = blockIdx.x * 256 + threadIdx.x;
    if (idx < 40960) {
        int col = idx & 255, subk = (idx >> 8) & 3, kc = (idx >> 10) & 7, L = idx >> 13;
        const float* W = (L == 0) ? W1 : (L == 1) ? W2 : (L == 2) ? W3 : (L == 3) ? W4 : W5;
        f16x8 vh;
        #pragma unroll
        for (int j = 0; j < 8; ++j) {
            int k = kc * 32 + subk * 8 + j;
            vh[j] = (f16)W[k * 256 + col];
        }
        int nf = col >> 4, l15 = col & 15, lane = subk * 16 + l15;
        *(f16x8*)(bh + (((L * 8 + kc) * 16 + nf) * 64 + lane) * 8) = vh;
    } else {
        int u = idx - 40960;
        if (u < 512) {
            int col = u & 15, subk = (u >> 4) & 3, kc = u >> 6;
            f16x8 vh;
            #pragma unroll
            for (int j = 0; j < 8; ++j) {
                int k = kc * 32 + subk * 8 + j;
                vh[j] = (f16)((col < 3) ? W6[k * 3 + col] : 0.f);
            }
            *(f16x8*)(b6h + (kc * 64 + subk * 16 + col) * 8) = vh;
        }
    }
}

// ---- main: round-12 structure (66 us) + anti-lockstep scheduling:
// (a) per-block s_sleep stagger so the 4 co-resident blocks/CU run phase-
//     shifted (one block's MFMA phase overlaps another's LDS/VALU phase);
// (b) s_setprio(1) around the MFMA kc-loop (T5: pays off given role
//     diversity the stagger creates).
// Layout/numerics identical to round 12.
__global__ __launch_bounds__(256) void pinn_ns_mfma(
    const float* __restrict__ t_, const float* __restrict__ x_, const float* __restrict__ y_,
    const float* __restrict__ W0, const float* __restrict__ b0,
    const float* __restrict__ b1, const float* __restrict__ b2,
    const float* __restrict__ b3, const float* __restrict__ b4,
    const float* __restrict__ b5, const float* __restrict__ b6,
    const f16* __restrict__ bh, const f16* __restrict__ b6h,
    float* __restrict__ out)
{
    __shared__ __align__(16) f16 afrag[NCH * 8 * 512];   // 40960 B

    const int tid = threadIdx.x;
    const int lane = tid & 63;
    const int nq = tid >> 6;           // wave: feature rows nq*64 .. +63
    const int q = lane >> 4;
    const int s = lane & 15;           // point index within tile
    const int gl = swz(lane);          // B-frag read granule
    const int p0 = blockIdx.x * PW;

    // ---- anti-lockstep stagger: offset co-resident blocks by ~3.8K cyc each
    {
        int ph = blockIdx.x & 3;
        for (int i = 0; i < ph * 4; ++i) __builtin_amdgcn_s_sleep(15);
    }

    // ---- layer 0: 3 -> 256 elementwise; write state B-frags.
    {
        float tv = t_[p0 + s], xv = x_[p0 + s], yv = y_[p0 + s];
        int fq0 = tid >> 4;            // 0..15
        #pragma unroll
        for (int i = 0; i < 4; ++i) {
            int fq = fq0 + 16 * i;     // feature quad 0..63
            int f0 = fq * 4;
            f32x4 w0 = *(const f32x4*)&W0[f0];
            f32x4 w1 = *(const f32x4*)&W0[256 + f0];
            f32x4 w2 = *(const f32x4*)&W0[512 + f0];
            f32x4 bb = *(const f32x4*)&b0[f0];
            f16x4 o[NCH];
            #pragma unroll
            for (int ff = 0; ff < 4; ++ff) {
                float z = tv * w0[ff] + xv * w1[ff] + yv * w2[ff] + bb[ff];
                float sv = __sinf(z), cv = __cosf(z);
                o[0][ff] = (f16)sv;
                o[1][ff] = (f16)(cv * w0[ff]);
                o[2][ff] = (f16)(cv * w1[ff]);
                o[3][ff] = (f16)(cv * w2[ff]);
                o[4][ff] = (f16)(-sv * (w1[ff] * w1[ff] + w2[ff] * w2[ff]));
            }
            int kc = fq >> 3;
            int g = swz(16 * ((fq >> 1) & 3) + s);
            int half = fq & 1;
            #pragma unroll
            for (int c = 0; c < NCH; ++c)
                *(f16x4*)&afrag[(c * 8 + kc) * 512 + g * 8 + half * 4] = o[c];
        }
    }
    __syncthreads();

    // ---- layers 1..5
    const float* bias[5] = {b1, b2, b3, b4, b5};
    const f16x8* A = (const f16x8*)afrag;
    for (int L = 0; L < 5; ++L) {
        const f16x8* wH = (const f16x8*)bh + L * 8192;
        f32x4 acc[NCH][4];
        #pragma unroll
        for (int c = 0; c < NCH; ++c)
            #pragma unroll
            for (int f = 0; f < 4; ++f)
                acc[c][f] = (f32x4){0.f, 0.f, 0.f, 0.f};

        f16x8 Wc[4];
        #pragma unroll
        for (int f = 0; f < 4; ++f)
            Wc[f] = wH[(nq * 4 + f) * 64 + lane];

        __builtin_amdgcn_s_setprio(1);
        #pragma unroll
        for (int kc = 0; kc < 8; ++kc) {
            f16x8 Wn[4];
            if (kc < 7) {
                #pragma unroll
                for (int f = 0; f < 4; ++f)
                    Wn[f] = wH[((kc + 1) * 16 + nq * 4 + f) * 64 + lane];
            }
            f16x8 S[NCH];
            #pragma unroll
            for (int c = 0; c < NCH; ++c)
                S[c] = A[(c * 8 + kc) * 64 + gl];
            #pragma unroll
            for (int c = 0; c < NCH; ++c)
                #pragma unroll
                for (int f = 0; f < 4; ++f)
                    acc[c][f] = __builtin_amdgcn_mfma_f32_16x16x32_f16(Wc[f], S[c], acc[c][f], 0, 0, 0);
            if (kc < 7) {
                #pragma unroll
                for (int f = 0; f < 4; ++f)
                    Wc[f] = Wn[f];
            }
        }
        __builtin_amdgcn_s_setprio(0);
        __syncthreads();  // all B-frag reads done before overwrite

        const float* bbp = bias[L];
        #pragma unroll
        for (int mf = 0; mf < 4; ++mf) {
            int fbase = nq * 64 + mf * 16 + 4 * q;   // 4 consecutive features
            f32x4 bq = *(const f32x4*)&bbp[fbase];
            f16x4 o[NCH];
            #pragma unroll
            for (int r = 0; r < 4; ++r) {
                float z = acc[0][mf][r] + bq[r];
                float zt = acc[1][mf][r], zx = acc[2][mf][r], zy = acc[3][mf][r];
                float zlap = acc[4][mf][r];
                float sv = __sinf(z), cv = __cosf(z);
                o[0][r] = (f16)sv;
                o[1][r] = (f16)(cv * zt);
                o[2][r] = (f16)(cv * zx);
                o[3][r] = (f16)(cv * zy);
                o[4][r] = (f16)(cv * zlap - sv * (zx * zx + zy * zy));
            }
            int kc = 2 * nq + (mf >> 1);
            int g = swz(16 * (2 * (mf & 1) + (q >> 1)) + s);
            int half = q & 1;
            #pragma unroll
            for (int c = 0; c < NCH; ++c)
                *(f16x4*)&afrag[(c * 8 + kc) * 512 + g * 8 + half * 4] = o[c];
        }
        __syncthreads();
    }

    // ---- layer 6: 256 -> 3 (cols 3..15 zero). Wave 0 computes all channels;
    // lanes q==0 hold (u,v,p) of point s in rows r=0..2 -> residuals in-lane.
    if (nq == 0) {
        f32x4 a6[NCH];
        #pragma unroll
        for (int c = 0; c < NCH; ++c)
            a6[c] = (f32x4){0.f, 0.f, 0.f, 0.f};
        const f16x8* w6 = (const f16x8*)b6h;
        #pragma unroll
        for (int kc = 0; kc < 8; ++kc) {
            f16x8 Wf = w6[kc * 64 + lane];
            #pragma unroll
            for (int c = 0; c < NCH; ++c)
                a6[c] = __builtin_amdgcn_mfma_f32_16x16x32_f16(Wf, A[(c * 8 + kc) * 64 + gl], a6[c], 0, 0, 0);
        }
        if (lane < 16) {
            int g = p0 + s;
            float u_   = a6[0][0] + b6[0], v_ = a6[0][1] + b6[1];
            float ut   = a6[1][0], vt   = a6[1][1];
            float ux   = a6[2][0], vx   = a6[2][1], px = a6[2][2];
            float uy   = a6[3][0], vy   = a6[3][1], py = a6[3][2];
            float ulap = a6[4][0], vlap = a6[4][1];
            out[g]            = ut + (u_ * ux + v_ * uy) + px - NU * ulap;
            out[NPTS + g]     = vt + (u_ * vx + v_ * vy) + py - NU * vlap;
            out[2 * NPTS + g] = ux + vy;
        }
    }
}

extern "C" void kernel_launch(void* const* d_in, const int* in_sizes, int n_in,
                              void* d_out, int out_size, void* d_ws, size_t ws_size,
                              hipStream_t stream) {
    const float* t_ = (const float*)d_in[0];
    const float* x_ = (const float*)d_in[1];
    const float* y_ = (const float*)d_in[2];
    const float* W[7];
    const float* b[7];
    for (int i = 0; i < 7; ++i) {
        W[i] = (const float*)d_in[3 + 2 * i];
        b[i] = (const float*)d_in[4 + 2 * i];
    }
    float* out = (float*)d_out;

    f16* bh  = (f16*)d_ws;               // 327680 f16
    f16* b6h = bh + 5 * 65536;           // 4096 f16

    hipLaunchKernelGGL(prep_kernel, dim3(162), dim3(256), 0, stream,
                       W[1], W[2], W[3], W[4], W[5], W[6], bh, b6h);
    hipLaunchKernelGGL(pinn_ns_mfma, dim3(NPTS / PW), dim3(256), 0, stream,
                       t_, x_, y_, W[0], b[0],
                       b[1], b[2], b[3], b[4], b[5], b[6],
                       bh, b6h, out);
}

// Round 15
// 151.932 us; speedup vs baseline: 1.0005x; 1.0005x over previous
//
#include <hip/hip_runtime.h>

#define NPTS 16384
#define PW 16
#define NCH 5
#define NU (1.0f / 100.0f)

typedef _Float16 f16;
typedef __attribute__((ext_vector_type(4))) _Float16 f16x4;
typedef __attribute__((ext_vector_type(8))) _Float16 f16x8;
typedef __attribute__((ext_vector_type(4))) float f32x4;

// granule swizzle within a 64-granule (16B each) tile: bijective, same on
// write and read; spreads writes/reads over all bank groups.
__device__ __forceinline__ int swz(int g) { return g ^ ((g >> 3) & 7); }

// ---- prep: W1..W5 (256x256) and W6 (256x3 zero-padded to 16 cols) -> MFMA
// fragment order, single f16 plane. Fragment (16x16x32): lane l holds
// M[k = kc*32 + 8*(l>>4) + j][col = nf*16 + (l&15)], j=0..7. Serves as the
// A-operand (A[m=col][k] = W^T) in the transposed GEMM.
__global__ __launch_bounds__(256) void prep_kernel(
    const float* __restrict__ W1, const float* __restrict__ W2,
    const float* __restrict__ W3, const float* __restrict__ W4,
    const float* __restrict__ W5, const float* __restrict__ W6,
    f16* __restrict__ bh, f16* __restrict__ b6h)
{
    int idx = blockIdx.x * 256 + threadIdx.x;
    if (idx < 40960) {
        int col = idx & 255, subk = (idx >> 8) & 3, kc = (idx >> 10) & 7, L = idx >> 13;
        const float* W = (L == 0) ? W1 : (L == 1) ? W2 : (L == 2) ? W3 : (L == 3) ? W4 : W5;
        f16x8 vh;
        #pragma unroll
        for (int j = 0; j < 8; ++j) {
            int k = kc * 32 + subk * 8 + j;
            vh[j] = (f16)W[k * 256 + col];
        }
        int nf = col >> 4, l15 = col & 15, lane = subk * 16 + l15;
        *(f16x8*)(bh + (((L * 8 + kc) * 16 + nf) * 64 + lane) * 8) = vh;
    } else {
        int u = idx - 40960;
        if (u < 512) {
            int col = u & 15, subk = (u >> 4) & 3, kc = u >> 6;
            f16x8 vh;
            #pragma unroll
            for (int j = 0; j < 8; ++j) {
                int k = kc * 32 + subk * 8 + j;
                vh[j] = (f16)((col < 3) ? W6[k * 3 + col] : 0.f);
            }
            *(f16x8*)(b6h + (kc * 64 + subk * 16 + col) * 8) = vh;
        }
    }
}

// ---- main: round-12 structure (66 us, best known good) + CORRECTED
// anti-lockstep stagger. Co-resident blocks on a CU differ by 256 in
// blockIdx (1024 blocks / 8 XCDs / 32 CUs), so the phase key must be
// (blockIdx >> 8) & 3 — r14's (blockIdx & 3) gave all co-residents the
// SAME sleep (no-op stagger, pure tail cost). Offsets ~1/4 layer each.
// No setprio this time (isolate one variable).
__global__ __launch_bounds__(256) void pinn_ns_mfma(
    const float* __restrict__ t_, const float* __restrict__ x_, const float* __restrict__ y_,
    const float* __restrict__ W0, const float* __restrict__ b0,
    const float* __restrict__ b1, const float* __restrict__ b2,
    const float* __restrict__ b3, const float* __restrict__ b4,
    const float* __restrict__ b5, const float* __restrict__ b6,
    const f16* __restrict__ bh, const f16* __restrict__ b6h,
    float* __restrict__ out)
{
    __shared__ __align__(16) f16 afrag[NCH * 8 * 512];   // 40960 B

    const int tid = threadIdx.x;
    const int lane = tid & 63;
    const int nq = tid >> 6;           // wave: feature rows nq*64 .. +63
    const int q = lane >> 4;
    const int s = lane & 15;           // point index within tile
    const int gl = swz(lane);          // B-frag read granule
    const int p0 = blockIdx.x * PW;

    // ---- anti-lockstep stagger (corrected key): co-resident blocks get
    // offsets 0 / ~7.7K / ~15.4K / ~23K cycles (~1/4 layer granularity).
    {
        int ph = (blockIdx.x >> 8) & 3;
        for (int i = 0; i < ph * 8; ++i) __builtin_amdgcn_s_sleep(15);
    }

    // ---- layer 0: 3 -> 256 elementwise; write state B-frags.
    {
        float tv = t_[p0 + s], xv = x_[p0 + s], yv = y_[p0 + s];
        int fq0 = tid >> 4;            // 0..15
        #pragma unroll
        for (int i = 0; i < 4; ++i) {
            int fq = fq0 + 16 * i;     // feature quad 0..63
            int f0 = fq * 4;
            f32x4 w0 = *(const f32x4*)&W0[f0];
            f32x4 w1 = *(const f32x4*)&W0[256 + f0];
            f32x4 w2 = *(const f32x4*)&W0[512 + f0];
            f32x4 bb = *(const f32x4*)&b0[f0];
            f16x4 o[NCH];
            #pragma unroll
            for (int ff = 0; ff < 4; ++ff) {
                float z = tv * w0[ff] + xv * w1[ff] + yv * w2[ff] + bb[ff];
                float sv = __sinf(z), cv = __cosf(z);
                o[0][ff] = (f16)sv;
                o[1][ff] = (f16)(cv * w0[ff]);
                o[2][ff] = (f16)(cv * w1[ff]);
                o[3][ff] = (f16)(cv * w2[ff]);
                o[4][ff] = (f16)(-sv * (w1[ff] * w1[ff] + w2[ff] * w2[ff]));
            }
            int kc = fq >> 3;
            int g = swz(16 * ((fq >> 1) & 3) + s);
            int half = fq & 1;
            #pragma unroll
            for (int c = 0; c < NCH; ++c)
                *(f16x4*)&afrag[(c * 8 + kc) * 512 + g * 8 + half * 4] = o[c];
        }
    }
    __syncthreads();

    // ---- layers 1..5
    const float* bias[5] = {b1, b2, b3, b4, b5};
    const f16x8* A = (const f16x8*)afrag;
    for (int L = 0; L < 5; ++L) {
        const f16x8* wH = (const f16x8*)bh + L * 8192;
        f32x4 acc[NCH][4];
        #pragma unroll
        for (int c = 0; c < NCH; ++c)
            #pragma unroll
            for (int f = 0; f < 4; ++f)
                acc[c][f] = (f32x4){0.f, 0.f, 0.f, 0.f};

        f16x8 Wc[4];
        #pragma unroll
        for (int f = 0; f < 4; ++f)
            Wc[f] = wH[(nq * 4 + f) * 64 + lane];

        #pragma unroll
        for (int kc = 0; kc < 8; ++kc) {
            f16x8 Wn[4];
            if (kc < 7) {
                #pragma unroll
                for (int f = 0; f < 4; ++f)
                    Wn[f] = wH[((kc + 1) * 16 + nq * 4 + f) * 64 + lane];
            }
            f16x8 S[NCH];
            #pragma unroll
            for (int c = 0; c < NCH; ++c)
                S[c] = A[(c * 8 + kc) * 64 + gl];
            #pragma unroll
            for (int c = 0; c < NCH; ++c)
                #pragma unroll
                for (int f = 0; f < 4; ++f)
                    acc[c][f] = __builtin_amdgcn_mfma_f32_16x16x32_f16(Wc[f], S[c], acc[c][f], 0, 0, 0);
            if (kc < 7) {
                #pragma unroll
                for (int f = 0; f < 4; ++f)
                    Wc[f] = Wn[f];
            }
        }
        __syncthreads();  // all B-frag reads done before overwrite

        const float* bbp = bias[L];
        #pragma unroll
        for (int mf = 0; mf < 4; ++mf) {
            int fbase = nq * 64 + mf * 16 + 4 * q;   // 4 consecutive features
            f32x4 bq = *(const f32x4*)&bbp[fbase];
            f16x4 o[NCH];
            #pragma unroll
            for (int r = 0; r < 4; ++r) {
                float z = acc[0][mf][r] + bq[r];
                float zt = acc[1][mf][r], zx = acc[2][mf][r], zy = acc[3][mf][r];
                float zlap = acc[4][mf][r];
                float sv = __sinf(z), cv = __cosf(z);
                o[0][r] = (f16)sv;
                o[1][r] = (f16)(cv * zt);
                o[2][r] = (f16)(cv * zx);
                o[3][r] = (f16)(cv * zy);
                o[4][r] = (f16)(cv * zlap - sv * (zx * zx + zy * zy));
            }
            int kc = 2 * nq + (mf >> 1);
            int g = swz(16 * (2 * (mf & 1) + (q >> 1)) + s);
            int half = q & 1;
            #pragma unroll
            for (int c = 0; c < NCH; ++c)
                *(f16x4*)&afrag[(c * 8 + kc) * 512 + g * 8 + half * 4] = o[c];
        }
        __syncthreads();
    }

    // ---- layer 6: 256 -> 3 (cols 3..15 zero). Wave 0 computes all channels;
    // lanes q==0 hold (u,v,p) of point s in rows r=0..2 -> residuals in-lane.
    if (nq == 0) {
        f32x4 a6[NCH];
        #pragma unroll
        for (int c = 0; c < NCH; ++c)
            a6[c] = (f32x4){0.f, 0.f, 0.f, 0.f};
        const f16x8* w6 = (const f16x8*)b6h;
        #pragma unroll
        for (int kc = 0; kc < 8; ++kc) {
            f16x8 Wf = w6[kc * 64 + lane];
            #pragma unroll
            for (int c = 0; c < NCH; ++c)
                a6[c] = __builtin_amdgcn_mfma_f32_16x16x32_f16(Wf, A[(c * 8 + kc) * 64 + gl], a6[c], 0, 0, 0);
        }
        if (lane < 16) {
            int g = p0 + s;
            float u_   = a6[0][0] + b6[0], v_ = a6[0][1] + b6[1];
            float ut   = a6[1][0], vt   = a6[1][1];
            float ux   = a6[2][0], vx   = a6[2][1], px = a6[2][2];
            float uy   = a6[3][0], vy   = a6[3][1], py = a6[3][2];
            float ulap = a6[4][0], vlap = a6[4][1];
            out[g]            = ut + (u_ * ux + v_ * uy) + px - NU * ulap;
            out[NPTS + g]     = vt + (u_ * vx + v_ * vy) + py - NU * vlap;
            out[2 * NPTS + g] = ux + vy;
        }
    }
}

extern "C" void kernel_launch(void* const* d_in, const int* in_sizes, int n_in,
                              void* d_out, int out_size, void* d_ws, size_t ws_size,
                              hipStream_t stream) {
    const float* t_ = (const float*)d_in[0];
    const float* x_ = (const float*)d_in[1];
    const float* y_ = (const float*)d_in[2];
    const float* W[7];
    const float* b[7];
    for (int i = 0; i < 7; ++i) {
        W[i] = (const float*)d_in[3 + 2 * i];
        b[i] = (const float*)d_in[4 + 2 * i];
    }
    float* out = (float*)d_out;

    f16* bh  = (f16*)d_ws;               // 327680 f16
    f16* b6h = bh + 5 * 65536;           // 4096 f16

    hipLaunchKernelGGL(prep_kernel, dim3(162), dim3(256), 0, stream,
                       W[1], W[2], W[3], W[4], W[5], W[6], bh, b6h);
    hipLaunchKernelGGL(pinn_ns_mfma, dim3(NPTS / PW), dim3(256), 0, stream,
                       t_, x_, y_, W[0], b[0],
                       b[1], b[2], b[3], b[4], b[5], b[6],
                       bh, b6h, out);
}